// Round 3
// baseline (2227.859 us; speedup 1.0000x reference)
//
#include <hip/hip_runtime.h>
#include <hip/hip_bf16.h>

#define HD 1024
#define BB 512
#define SS 64
#define N3 3072
#define NC 9216      // 3 * N3  (gi2 | gh1 | gh2)
#define ND 9
#define VC 4
#define KI 832       // padded K for init GEMM (784 -> 13*64)

typedef __attribute__((ext_vector_type(8))) short bf16x8;
typedef __attribute__((ext_vector_type(4))) float f32x4;

__device__ __forceinline__ ushort f2b(float f) {
    unsigned u = __builtin_bit_cast(unsigned, f);
    u += 0x7fffu + ((u >> 16) & 1u);          // round-to-nearest-even
    return (ushort)(u >> 16);
}

__device__ __forceinline__ void gld_lds16(const void* g, void* l) {
    __builtin_amdgcn_global_load_lds(
        (const __attribute__((address_space(1))) unsigned int*)g,
        (__attribute__((address_space(3))) unsigned int*)l, 16, 0, 0);
}

// ============================================================================
// prep: Wcat bf16 = [W_ih2 ; W_hh1 ; W_hh2], each [3072][1024]
// ============================================================================
__global__ __launch_bounds__(256) void prep_w(
    const float* __restrict__ Wih2, const float* __restrict__ Whh1,
    const float* __restrict__ Whh2, ushort* __restrict__ Wcat)
{
    const int row = blockIdx.x;
    const float* src = row < 3072 ? Wih2 + (size_t)row * HD
                     : row < 6144 ? Whh1 + (size_t)(row - 3072) * HD
                                  : Whh2 + (size_t)(row - 6144) * HD;
    const int c = threadIdx.x * 4;
    float4 v = *(const float4*)(src + c);
    ushort4 o;
    o.x = f2b(v.x); o.y = f2b(v.y); o.z = f2b(v.z); o.w = f2b(v.w);
    *(ushort4*)(Wcat + (size_t)row * HD + c) = o;
}

// Wt1[c][g] = W_ih1[g][c]   (22 x 3072, f32)
__global__ __launch_bounds__(256) void prep_wt1(
    const float* __restrict__ Wih1, float* __restrict__ Wt1)
{
    const int g = blockIdx.x * 256 + threadIdx.x;
    #pragma unroll
    for (int c = 0; c < 22; ++c)
        Wt1[c * N3 + g] = Wih1[(size_t)g * 22 + c];
}

// Acat bf16 [512][832]: [z | note_encoded | genre | 0-pad]
__global__ __launch_bounds__(256) void prep_acat(
    const float* __restrict__ z, const float* __restrict__ ne,
    const float* __restrict__ gc, ushort* __restrict__ Acat)
{
    const int b = blockIdx.x;
    const int t = threadIdx.x;
    if (t >= 208) return;
    const int c = t * 4;
    float4 v = make_float4(0.f, 0.f, 0.f, 0.f);
    if (c < 256)      v = *(const float4*)(z  + (size_t)b * 256 + c);
    else if (c < 768) v = *(const float4*)(ne + (size_t)b * 512 + (c - 256));
    else if (c < 784) v = *(const float4*)(gc + (size_t)b * 16  + (c - 768));
    ushort4 o;
    o.x = f2b(v.x); o.y = f2b(v.y); o.z = f2b(v.z); o.w = f2b(v.w);
    *(ushort4*)(Acat + (size_t)b * KI + c) = o;
}

// W_inb bf16 [1024][832] zero-padded from W_in [1024][784]
__global__ __launch_bounds__(256) void prep_win(
    const float* __restrict__ W_in, ushort* __restrict__ W_inb)
{
    const int r = blockIdx.x;
    const int t = threadIdx.x;
    if (t >= 208) return;
    const int c = t * 4;
    ushort4 o = {0, 0, 0, 0};
    if (c < 784) {
        float4 v = *(const float4*)(W_in + (size_t)r * 784 + c);
        o.x = f2b(v.x); o.y = f2b(v.y); o.z = f2b(v.z); o.w = f2b(v.w);
    }
    *(ushort4*)(W_inb + (size_t)r * KI + c) = o;
}

// ============================================================================
// gemm3: C[512, 9216] = [h1b@Wih2^T | h1b@Whh1^T | h2b@Whh2^T]
// block 64(m) x 128(n), BK=64, 4 waves (2x2), wave tile 32x64.
// mfma_f32_16x16x32_bf16; global_load_lds w16 with XOR-swizzled source;
// XCD-chunked bijective block swizzle (grid = 8 x gridDim.y).
// ============================================================================
__global__ __launch_bounds__(256) void gemm3(
    const ushort* __restrict__ h1b, const ushort* __restrict__ h2b,
    const ushort* __restrict__ Wcat, float* __restrict__ Cbuf, int ntb)
{
    __shared__ __align__(16) ushort As[64 * 64];
    __shared__ __align__(16) ushort Bs[128 * 64];

    const int flat = blockIdx.x + (blockIdx.y << 3);
    const int id   = (flat & 7) * gridDim.y + (flat >> 3);  // XCD-contiguous
    const int mt   = id & 7;
    const int n2   = (id >> 3) + ntb;          // 128-col tile, 0..71
    const int bm   = mt << 6;

    const ushort* Amat = (n2 < 48) ? h1b : h2b;
    const ushort* Wb   = Wcat + (size_t)(n2 << 7) * HD;

    const int tid = threadIdx.x;
    const int w   = tid >> 6;
    const int l   = tid & 63;
    const int lr  = l >> 3;                    // 0..7
    const int sw  = ((l & 7) ^ lr) << 3;       // swizzled chunk (elements)

    const ushort* Ag0 = Amat + (size_t)(bm + 16 * w + lr) * HD + sw;
    const ushort* Ag1 = Ag0 + 8 * HD;
    const ushort* Bg0 = Wb + (size_t)(32 * w + lr) * HD + sw;
    const ushort* Bg1 = Bg0 + 8 * HD;
    const ushort* Bg2 = Bg0 + 16 * HD;
    const ushort* Bg3 = Bg0 + 24 * HD;
    ushort* Al0 = As + (16 * w) * 64;
    ushort* Al1 = As + (16 * w + 8) * 64;
    ushort* Bl0 = Bs + (32 * w) * 64;
    ushort* Bl1 = Bs + (32 * w + 8) * 64;
    ushort* Bl2 = Bs + (32 * w + 16) * 64;
    ushort* Bl3 = Bs + (32 * w + 24) * 64;

    const int wm2 = w >> 1;                    // 0/1 : m half
    const int wn2 = w & 1;                     // 0/1 : n half
    const int fr  = l & 15;
    const int fc  = l >> 4;

    f32x4 acc[2][4] = {};

    for (int kt = 0; kt < 16; ++kt) {
        const int ko = kt << 6;
        __syncthreads();
        gld_lds16(Ag0 + ko, Al0);
        gld_lds16(Ag1 + ko, Al1);
        gld_lds16(Bg0 + ko, Bl0);
        gld_lds16(Bg1 + ko, Bl1);
        gld_lds16(Bg2 + ko, Bl2);
        gld_lds16(Bg3 + ko, Bl3);
        __syncthreads();
        #pragma unroll
        for (int kk = 0; kk < 2; ++kk) {
            const int c = (kk << 2) + fc;
            bf16x8 a[2], b[4];
            #pragma unroll
            for (int i = 0; i < 2; ++i) {
                const int ra = (wm2 << 5) + (i << 4) + fr;
                a[i] = *(const bf16x8*)(As + ra * 64 + ((c ^ (ra & 7)) << 3));
            }
            #pragma unroll
            for (int j = 0; j < 4; ++j) {
                const int rb = (wn2 << 6) + (j << 4) + fr;
                b[j] = *(const bf16x8*)(Bs + rb * 64 + ((c ^ (rb & 7)) << 3));
            }
            #pragma unroll
            for (int i = 0; i < 2; ++i)
                #pragma unroll
                for (int j = 0; j < 4; ++j)
                    acc[i][j] = __builtin_amdgcn_mfma_f32_16x16x32_bf16(a[i], b[j], acc[i][j], 0, 0, 0);
        }
    }

    const int bn = n2 << 7;
    #pragma unroll
    for (int i = 0; i < 2; ++i) {
        const int row0 = bm + (wm2 << 5) + (i << 4) + (fc << 2);
        #pragma unroll
        for (int r = 0; r < 4; ++r) {
            float* Crow = Cbuf + (size_t)(row0 + r) * NC + bn + (wn2 << 6) + fr;
            Crow[0]  = acc[i][0][r];
            Crow[16] = acc[i][1][r];
            Crow[32] = acc[i][2][r];
            Crow[48] = acc[i][3][r];
        }
    }
}

// ============================================================================
// gemm_init: h1 = tanh(Acat @ W_inb^T + b_in), writes h1 f32 + h1b bf16.
// Same structure; K=832 (13 steps), strides KI. grid (8,8).
// ============================================================================
__global__ __launch_bounds__(256) void gemm_init(
    const ushort* __restrict__ Acat, const ushort* __restrict__ W_inb,
    const float* __restrict__ b_in, float* __restrict__ h1, ushort* __restrict__ h1b)
{
    __shared__ __align__(16) ushort As[64 * 64];
    __shared__ __align__(16) ushort Bs[128 * 64];

    const int flat = blockIdx.x + (blockIdx.y << 3);
    const int id   = (flat & 7) * gridDim.y + (flat >> 3);
    const int mt   = id & 7;
    const int n2   = id >> 3;                  // 0..7
    const int bm   = mt << 6;

    const ushort* Wb = W_inb + (size_t)(n2 << 7) * KI;

    const int tid = threadIdx.x;
    const int w   = tid >> 6;
    const int l   = tid & 63;
    const int lr  = l >> 3;
    const int sw  = ((l & 7) ^ lr) << 3;

    const ushort* Ag0 = Acat + (size_t)(bm + 16 * w + lr) * KI + sw;
    const ushort* Ag1 = Ag0 + 8 * KI;
    const ushort* Bg0 = Wb + (size_t)(32 * w + lr) * KI + sw;
    const ushort* Bg1 = Bg0 + 8 * KI;
    const ushort* Bg2 = Bg0 + 16 * KI;
    const ushort* Bg3 = Bg0 + 24 * KI;
    ushort* Al0 = As + (16 * w) * 64;
    ushort* Al1 = As + (16 * w + 8) * 64;
    ushort* Bl0 = Bs + (32 * w) * 64;
    ushort* Bl1 = Bs + (32 * w + 8) * 64;
    ushort* Bl2 = Bs + (32 * w + 16) * 64;
    ushort* Bl3 = Bs + (32 * w + 24) * 64;

    const int wm2 = w >> 1;
    const int wn2 = w & 1;
    const int fr  = l & 15;
    const int fc  = l >> 4;

    f32x4 acc[2][4] = {};

    for (int kt = 0; kt < 13; ++kt) {
        const int ko = kt << 6;
        __syncthreads();
        gld_lds16(Ag0 + ko, Al0);
        gld_lds16(Ag1 + ko, Al1);
        gld_lds16(Bg0 + ko, Bl0);
        gld_lds16(Bg1 + ko, Bl1);
        gld_lds16(Bg2 + ko, Bl2);
        gld_lds16(Bg3 + ko, Bl3);
        __syncthreads();
        #pragma unroll
        for (int kk = 0; kk < 2; ++kk) {
            const int c = (kk << 2) + fc;
            bf16x8 a[2], b[4];
            #pragma unroll
            for (int i = 0; i < 2; ++i) {
                const int ra = (wm2 << 5) + (i << 4) + fr;
                a[i] = *(const bf16x8*)(As + ra * 64 + ((c ^ (ra & 7)) << 3));
            }
            #pragma unroll
            for (int j = 0; j < 4; ++j) {
                const int rb = (wn2 << 6) + (j << 4) + fr;
                b[j] = *(const bf16x8*)(Bs + rb * 64 + ((c ^ (rb & 7)) << 3));
            }
            #pragma unroll
            for (int i = 0; i < 2; ++i)
                #pragma unroll
                for (int j = 0; j < 4; ++j)
                    acc[i][j] = __builtin_amdgcn_mfma_f32_16x16x32_bf16(a[i], b[j], acc[i][j], 0, 0, 0);
        }
    }

    const int bn = (n2 << 7) + (wn2 << 6) + fr;
    float bj[4];
    #pragma unroll
    for (int j = 0; j < 4; ++j) bj[j] = b_in[bn + (j << 4)];
    #pragma unroll
    for (int i = 0; i < 2; ++i) {
        const int row0 = bm + (wm2 << 5) + (i << 4) + (fc << 2);
        #pragma unroll
        for (int r = 0; r < 4; ++r) {
            #pragma unroll
            for (int j = 0; j < 4; ++j) {
                const float v = tanhf(acc[i][j][r] + bj[j]);
                const size_t idx = (size_t)(row0 + r) * HD + bn + (j << 4);
                h1[idx]  = v;
                h1b[idx] = f2b(v);
            }
        }
    }
}

// ============================================================================
// gru1_first: step-0 GRU1 (out_prev = 0); writes h1,h1b and copies to h2,h2b.
// ============================================================================
__global__ __launch_bounds__(1024) void gru1_first(
    const float* __restrict__ Cbuf, float* __restrict__ h1, ushort* __restrict__ h1b,
    float* __restrict__ h2, ushort* __restrict__ h2b,
    const float* __restrict__ note, const float* __restrict__ velc,
    const float* __restrict__ Wt1, const float* __restrict__ b_ih1,
    const float* __restrict__ b_hh1)
{
    __shared__ float inp[22];
    const int b = blockIdx.x;
    const int j = threadIdx.x;

    if (j < 22) {
        float v = 0.f;
        if (j >= 9 && j < 18) v = note[(size_t)b * (SS * ND) + (j - 9)];
        else if (j >= 18)     v = velc[(size_t)b * (SS * VC) + (j - 18)];
        inp[j] = v;
    }
    __syncthreads();

    float ir = b_ih1[j], iz = b_ih1[HD + j], inn = b_ih1[2 * HD + j];
    #pragma unroll
    for (int c = 0; c < 22; ++c) {
        const float x = inp[c];
        const float* wr = Wt1 + c * N3;
        ir  = fmaf(x, wr[j],          ir);
        iz  = fmaf(x, wr[HD + j],     iz);
        inn = fmaf(x, wr[2 * HD + j], inn);
    }

    const float* g = Cbuf + (size_t)b * NC + N3;     // gh1 section
    const float hr = g[j]          + b_hh1[j];
    const float hz = g[HD + j]     + b_hh1[HD + j];
    const float hn = g[2 * HD + j] + b_hh1[2 * HD + j];

    const float rg = 1.f / (1.f + __expf(-(ir + hr)));
    const float zg = 1.f / (1.f + __expf(-(iz + hz)));
    const float n  = tanhf(inn + rg * hn);
    const float hnew = (1.f - zg) * n + zg * h1[(size_t)b * HD + j];
    const ushort hb = f2b(hnew);
    h1[(size_t)b * HD + j]  = hnew;
    h1b[(size_t)b * HD + j] = hb;
    h2[(size_t)b * HD + j]  = hnew;
    h2b[(size_t)b * HD + j] = hb;
}

// ============================================================================
// pw_fused(step): GRU2 -> h2,h2b ; out[step] ; GRU1(step+1) -> h1,h1b.
// grid (512) x 1024 threads.
// ============================================================================
__global__ __launch_bounds__(1024) void pw_fused(
    const float* __restrict__ Cbuf, float* __restrict__ h1, ushort* __restrict__ h1b,
    float* __restrict__ h2, ushort* __restrict__ h2b,
    const float* __restrict__ note, const float* __restrict__ velc,
    const float* __restrict__ Wt1,
    const float* __restrict__ b_ih1, const float* __restrict__ b_hh1,
    const float* __restrict__ b_ih2, const float* __restrict__ b_hh2,
    const float* __restrict__ W_out, const float* __restrict__ b_out,
    float* __restrict__ dout, int step)
{
    __shared__ float hs[HD];
    __shared__ float inp[22];
    const int b = blockIdx.x;
    const int j = threadIdx.x;

    // stage next-step note/velc while GRU2 runs
    if (step + 1 < SS && j >= 9 && j < 22) {
        inp[j] = (j < 18) ? note[(size_t)b * (SS * ND) + (step + 1) * ND + (j - 9)]
                          : velc[(size_t)b * (SS * VC) + (step + 1) * VC + (j - 18)];
    }

    const float* gi = Cbuf + (size_t)b * NC;          // gi2
    const float* gh = gi + 2 * N3;                    // gh2

    const float ir  = gi[j]          + b_ih2[j];
    const float hr  = gh[j]          + b_hh2[j];
    const float iz  = gi[HD + j]     + b_ih2[HD + j];
    const float hz  = gh[HD + j]     + b_hh2[HD + j];
    const float inn = gi[2 * HD + j] + b_ih2[2 * HD + j];
    const float hn  = gh[2 * HD + j] + b_hh2[2 * HD + j];

    const float rg = 1.f / (1.f + __expf(-(ir + hr)));
    const float zg = 1.f / (1.f + __expf(-(iz + hz)));
    const float n  = tanhf(inn + rg * hn);
    const float hnew = (1.f - zg) * n + zg * h2[(size_t)b * HD + j];
    h2[(size_t)b * HD + j]  = hnew;
    h2b[(size_t)b * HD + j] = f2b(hnew);
    hs[j] = hnew;
    __syncthreads();

    // out[b, step, :]
    const int w = j >> 6;
    const int t = j & 63;
    if (w < ND) {
        float a = 0.f;
        const float* wr = W_out + (size_t)w * HD;
        #pragma unroll
        for (int k = 0; k < HD / 64; ++k)
            a = fmaf(hs[t + k * 64], wr[t + k * 64], a);
        #pragma unroll
        for (int off = 32; off > 0; off >>= 1) a += __shfl_down(a, off);
        if (t == 0) {
            const float o = 1.f / (1.f + __expf(-(a + b_out[w])));
            dout[(size_t)b * (SS * ND) + step * ND + w] = o;
            inp[w] = o;
        }
    }
    __syncthreads();

    // GRU1 for step+1
    if (step + 1 < SS) {
        float xir = b_ih1[j], xiz = b_ih1[HD + j], xinn = b_ih1[2 * HD + j];
        #pragma unroll
        for (int c = 0; c < 22; ++c) {
            const float x = inp[c];
            const float* wr = Wt1 + c * N3;
            xir  = fmaf(x, wr[j],          xir);
            xiz  = fmaf(x, wr[HD + j],     xiz);
            xinn = fmaf(x, wr[2 * HD + j], xinn);
        }
        const float* g1 = Cbuf + (size_t)b * NC + N3;  // gh1 (for step+1)
        const float hr1 = g1[j]          + b_hh1[j];
        const float hz1 = g1[HD + j]     + b_hh1[HD + j];
        const float hn1 = g1[2 * HD + j] + b_hh1[2 * HD + j];

        const float rg1 = 1.f / (1.f + __expf(-(xir + hr1)));
        const float zg1 = 1.f / (1.f + __expf(-(xiz + hz1)));
        const float n1  = tanhf(xinn + rg1 * hn1);
        const float h1new = (1.f - zg1) * n1 + zg1 * h1[(size_t)b * HD + j];
        h1[(size_t)b * HD + j]  = h1new;
        h1b[(size_t)b * HD + j] = f2b(h1new);
    }
}

// ============================================================================
extern "C" void kernel_launch(void* const* d_in, const int* in_sizes, int n_in,
                              void* d_out, int out_size, void* d_ws, size_t ws_size,
                              hipStream_t stream)
{
    const float* z     = (const float*)d_in[0];
    const float* ne    = (const float*)d_in[1];
    const float* note  = (const float*)d_in[3];
    const float* velc  = (const float*)d_in[4];
    const float* gc    = (const float*)d_in[5];
    const float* W_in  = (const float*)d_in[6];
    const float* b_in  = (const float*)d_in[7];
    const float* W_ih1 = (const float*)d_in[8];
    const float* W_hh1 = (const float*)d_in[9];
    const float* b_ih1 = (const float*)d_in[10];
    const float* b_hh1 = (const float*)d_in[11];
    const float* W_ih2 = (const float*)d_in[12];
    const float* W_hh2 = (const float*)d_in[13];
    const float* b_ih2 = (const float*)d_in[14];
    const float* b_hh2 = (const float*)d_in[15];
    const float* W_out = (const float*)d_in[16];
    const float* b_out = (const float*)d_in[17];
    float* out = (float*)d_out;

    // workspace layout (same 44 MB footprint as round 2)
    float*  h1   = (float*)d_ws;                     // [512*1024]
    float*  h2   = h1 + BB * HD;                     // [512*1024]
    float*  Cbuf = h2 + BB * HD;                     // [512*9216]
    float*  Wt1  = Cbuf + (size_t)BB * NC;           // [22*3072]
    ushort* h1b  = (ushort*)(Wt1 + 22 * N3);         // [512*1024]
    ushort* h2b  = h1b + BB * HD;                    // [512*1024]
    ushort* Wcat = h2b + BB * HD;                    // [9216*1024]
    // init-only buffers aliased into Cbuf (dead before gemm_pro writes Cbuf)
    ushort* Acat  = (ushort*)Cbuf;                   // [512*832]
    ushort* W_inb = Acat + (size_t)BB * KI;          // [1024*832]

    prep_w   <<<dim3(NC),  256, 0, stream>>>(W_ih2, W_hh1, W_hh2, Wcat);
    prep_wt1 <<<dim3(12),  256, 0, stream>>>(W_ih1, Wt1);
    prep_acat<<<dim3(BB),  256, 0, stream>>>(z, ne, gc, Acat);
    prep_win <<<dim3(HD),  256, 0, stream>>>(W_in, W_inb);

    gemm_init<<<dim3(8, 8), 256, 0, stream>>>(Acat, W_inb, b_in, h1, h1b);

    // prologue: gh1(0)  (128-col tiles 24..47)
    gemm3<<<dim3(8, 24), 256, 0, stream>>>(h1b, h2b, Wcat, Cbuf, 24);
    gru1_first<<<dim3(BB), 1024, 0, stream>>>(Cbuf, h1, h1b, h2, h2b,
                                              note, velc, Wt1, b_ih1, b_hh1);

    for (int s = 0; s < SS; ++s) {
        // gi2(s) | gh1(s+1) | gh2(s)
        gemm3<<<dim3(8, 72), 256, 0, stream>>>(h1b, h2b, Wcat, Cbuf, 0);
        pw_fused<<<dim3(BB), 1024, 0, stream>>>(Cbuf, h1, h1b, h2, h2b,
                                                note, velc, Wt1,
                                                b_ih1, b_hh1, b_ih2, b_hh2,
                                                W_out, b_out, out, s);
    }
}